// Round 12
// baseline (66.509 us; speedup 1.0000x reference)
//
#include <hip/hip_runtime.h>

#define SS 4096
#define CC 128
#define BB 32
#define KW 25
#define PADW 12
#define STRIP 256           // rows per K1 block
#define KCH 32              // rows per chunk
#define NCHK (STRIP / KCH)  // 8 chunks per block
#define RING 64             // ring rows (32 KiB)
#define NSTRIP (SS / STRIP) // 16
#define NSERIES (BB * CC)   // 4096
#define NXCD 8

typedef float f4v __attribute__((ext_vector_type(4)));
typedef float f2v __attribute__((ext_vector_type(2)));

// ---------------- K1: ring-buffer trend + stats ------------------------------
// 512 blocks x 512 threads (2 blocks/CU, 4 waves/SIMD). Block owns a 256-row
// strip of one batch; 64-row LDS ring slides down it: per 32-row chunk only
// the 32 NEW rows are loaded (halo = 24/256 = 9%). Trend math is the bit-exact
// ascending 25-add chain; stats use the exact f32 trend.
__global__ __launch_bounds__(512, 4)
void k1_ring(const float* __restrict__ x, float* __restrict__ trend,
             float* __restrict__ stats) {
    __shared__ f2v ring[RING][64];            // 32 KiB

    const int blk = blockIdx.x;               // 0..511
    const int b = blk >> 4;                   // batch
    const int st = blk & 15;                  // strip
    const int s0 = st * STRIP;
    const int tid = threadIdx.x;
    const int cp = tid & 63;                  // channel pair (wave = one rg)
    const int rg = tid >> 6;                  // row group 0..7 (4 rows/chunk)
    const float* __restrict__ xb = x + (size_t)b * SS * CC;
    f2v* __restrict__ tb = (f2v*)(trend + (size_t)b * SS * CC);

    // ---- prologue: stage rows s0-12 .. s0+43 (56 rows, 7 f2v/thread) ----
    #pragma unroll
    for (int t = 0; t < 7; ++t) {
        const int idx = t * 512 + tid;        // 0..3583
        const int rl = idx >> 6;              // 0..55
        const int cq = idx & 63;
        const int r = s0 - PADW + rl;
        const int cr = r < 0 ? 0 : r;         // r < SS always here
        f2v v = *(const f2v*)(xb + (size_t)cr * CC + 2 * cq);
        if (r < 0) v = (f2v){0.f, 0.f};
        ring[r & (RING - 1)][cq] = v;
    }

    f2v Sx_e = {0,0}, Sx_o = {0,0}, Sx2 = {0,0};
    f2v St_e = {0,0}, St_o = {0,0}, St2 = {0,0}, Sxt = {0,0};

    for (int c = 0; c < NCHK; ++c) {
        __syncthreads();                      // ring holds rows [Rb-12, Rb+43]
        const int Rb = s0 + c * KCH;
        const bool more = (c + 1 < NCHK);

        // issue next chunk's 32 rows (Rb+44 .. Rb+75) into registers
        f2v nv[4];
        if (more) {
            #pragma unroll
            for (int t = 0; t < 4; ++t) {
                const int idx = t * 512 + tid;       // 0..2047
                const int r = Rb + 44 + (idx >> 6);  // may exceed SS-1
                const int cr = r >= SS ? SS - 1 : r;
                nv[t] = *(const f2v*)(xb + (size_t)cr * CC + 2 * ((idx & 63)));
            }
        }

        // compute rows Rb + rg*4 .. +3 from the ring
        const int r0 = Rb + rg * 4;           // even -> parity == i&1
        f2v win[KW];
        #pragma unroll
        for (int j = 0; j < KW; ++j)
            win[j] = ring[(r0 - PADW + j) & (RING - 1)][cp];

        #pragma unroll
        for (int i = 0; i < 4; ++i) {
            // fp32 sequential sum, ascending window order == XLA reduce_window
            float ax = win[0].x, ay = win[0].y;
            #pragma unroll
            for (int j = 1; j < KW; ++j) { ax += win[j].x; ay += win[j].y; }
            f2v tf;
            tf.x = ax / 25.0f;                // IEEE f32 divide, matches sums/K
            tf.y = ay / 25.0f;
            tb[(r0 + i) * 64 + cp] = tf;      // cached: K3 re-reads trend

            const f2v xv = win[PADW];         // x[s]
            if (i & 1) { Sx_o.x += xv.x; Sx_o.y += xv.y; St_o.x += tf.x; St_o.y += tf.y; }
            else       { Sx_e.x += xv.x; Sx_e.y += xv.y; St_e.x += tf.x; St_e.y += tf.y; }
            Sx2.x += xv.x * xv.x;  Sx2.y += xv.y * xv.y;
            St2.x += tf.x * tf.x;  St2.y += tf.y * tf.y;
            Sxt.x += xv.x * tf.x;  Sxt.y += xv.y * tf.y;

            #pragma unroll
            for (int j = 0; j < KW - 1; ++j) win[j] = win[j + 1];
            if (i < 3) win[KW - 1] = ring[(r0 + i + PADW + 1) & (RING - 1)][cp];
        }

        __syncthreads();                      // all ring reads done
        if (more) {
            // commit new rows; they overwrite slots of dead rows (< Rb+20)
            #pragma unroll
            for (int t = 0; t < 4; ++t) {
                const int idx = t * 512 + tid;
                const int r = Rb + 44 + (idx >> 6);
                f2v v = nv[t];
                if (r >= SS) v = (f2v){0.f, 0.f};
                ring[r & (RING - 1)][idx & 63] = v;
            }
        }
    }

    // ---- combine 8 row-groups deterministically (reuse ring LDS) ----
    __syncthreads();
    float* rr = (float*)ring;                 // [g=rg-1][j<7][cp] f2v
    if (rg > 0) {
        f2v* me = (f2v*)rr + (size_t)(rg - 1) * 7 * 64 + cp;
        me[0 * 64] = Sx_e; me[1 * 64] = Sx_o; me[2 * 64] = Sx2;
        me[3 * 64] = St_e; me[4 * 64] = St_o; me[5 * 64] = St2;
        me[6 * 64] = Sxt;
    }
    __syncthreads();
    if (rg == 0) {
        #pragma unroll
        for (int g = 0; g < 7; ++g) {
            const f2v* gp = (const f2v*)rr + (size_t)g * 7 * 64 + cp;
            Sx_e.x += gp[0*64].x; Sx_e.y += gp[0*64].y;
            Sx_o.x += gp[1*64].x; Sx_o.y += gp[1*64].y;
            Sx2.x  += gp[2*64].x; Sx2.y  += gp[2*64].y;
            St_e.x += gp[3*64].x; St_e.y += gp[3*64].y;
            St_o.x += gp[4*64].x; St_o.y += gp[4*64].y;
            St2.x  += gp[5*64].x; St2.y  += gp[5*64].y;
            Sxt.x  += gp[6*64].x; Sxt.y  += gp[6*64].y;
        }
        const int series = b * CC + 2 * cp;   // float2-aligned
        float* sp = stats + (size_t)st * NSERIES + series;
        const size_t jstride = (size_t)NSTRIP * NSERIES;
        *(f2v*)(sp + 0 * jstride) = Sx_e;
        *(f2v*)(sp + 1 * jstride) = Sx_o;
        *(f2v*)(sp + 2 * jstride) = Sx2;
        *(f2v*)(sp + 3 * jstride) = St_e;
        *(f2v*)(sp + 4 * jstride) = St_o;
        *(f2v*)(sp + 5 * jstride) = St2;
        *(f2v*)(sp + 6 * jstride) = Sxt;
    }
}

// ---------------- K2: fold 16 strip-partials + compute cond ------------------
__global__ __launch_bounds__(256)
void k2_finalize(const float* __restrict__ stats, float* __restrict__ condf) {
    const int j = threadIdx.x >> 5;          // stat index 0..7 (7 used)
    const int sl = threadIdx.x & 31;
    const int series = blockIdx.x * 32 + sl; // 0..4095 (128 blocks)
    const size_t jstride = (size_t)NSTRIP * NSERIES;

    __shared__ float red[32][8];
    if (j < 7) {
        const float* p = stats + j * jstride + series;
        float a = 0.f;
        #pragma unroll
        for (int k = 0; k < NSTRIP; ++k) a += p[(size_t)k * NSERIES];
        red[sl][j] = a;
    }
    __syncthreads();
    if (threadIdx.x < 32) {
        const int me = threadIdx.x;
        const float Sx_e = red[me][0], Sx_o = red[me][1], Sx2 = red[me][2];
        const float St_e = red[me][3], St_o = red[me][4], St2 = red[me][5];
        const float Sxt = red[me][6];

        const float Sf = (float)SS;
        const float halfS = 0.5f * Sf;
        const float c_e = Sx_o / Sf;         // opposite-parity mean at even n
        const float c_o = Sx_e / Sf;
        const float sum_c = halfS * (c_e + c_o);
        const float sumsq_c = halfS * (c_e * c_e + c_o * c_o);

        const float Sw_e = 0.5f * Sx_e - St_e;
        const float Sw_o = 0.5f * Sx_o - St_o;
        const float Sw2 = 0.25f * Sx2 - Sxt + St2;

        // v1 = resid = w + c_p
        const float s1 = (Sw_e + Sw_o) + sum_c;
        const float q1 = Sw2 + 2.f * (c_e * Sw_e + c_o * Sw_o) + sumsq_c;
        const float var1 = (q1 - s1 * s1 / Sf) / (Sf - 1.f);
        // v2 = trend + resid = 0.5x + c_p
        const float s2 = 0.5f * (Sx_e + Sx_o) + sum_c;
        const float q2 = 0.25f * Sx2 + (c_e * Sx_e + c_o * Sx_o) + sumsq_c;
        const float var2 = (q2 - s2 * s2 / Sf) / (Sf - 1.f);
        // v3 = seasonal0 + resid = x - trend
        const float Sa = (Sx_e + Sx_o) - (St_e + St_o);
        const float Sa2 = Sx2 - 2.f * Sxt + St2;
        const float var3 = (Sa2 - Sa * Sa / Sf) / (Sf - 1.f);

        const float d_t = 1.f - var1 / (var2 + 1e-8f);
        const float d_s = 1.f - var1 / (var3 + 1e-8f);
        condf[blockIdx.x * 32 + me] = (d_t > 0.5f || d_s > 0.5f) ? 1.f : 0.f;
    }
}

// ---------------- K3: seasonal = cond ? x/(trend+eps) : x - trend ------------
// Streaming: x and trend are L3-resident after K1; nt store for seasonal.
__global__ __launch_bounds__(256)
void k3_seasonal(const float* __restrict__ x, const float* __restrict__ trend,
                 const float* __restrict__ condf, float* __restrict__ seasonal) {
    const int vb = (blockIdx.x % NXCD) * 256 + blockIdx.x / NXCD;  // 2048 blocks
    const int qbase = vb * 2048;
    #pragma unroll
    for (int t = 0; t < 8; ++t) {
        const int q = qbase + t * 256 + threadIdx.x;
        const int e = q * 4;
        const int b = e >> 19;          // / (SS*CC)
        const int c = e & (CC - 1);     // quad-aligned channel base
        const f4v x4 = *(const f4v*)(x + e);
        const f4v t4 = *(const f4v*)(trend + e);
        const f4v c4 = *(const f4v*)(condf + b * CC + c);
        f4v o;
        o.x = (c4.x > 0.5f) ? x4.x / (t4.x + 1e-8f) : x4.x - t4.x;
        o.y = (c4.y > 0.5f) ? x4.y / (t4.y + 1e-8f) : x4.y - t4.y;
        o.z = (c4.z > 0.5f) ? x4.z / (t4.z + 1e-8f) : x4.z - t4.z;
        o.w = (c4.w > 0.5f) ? x4.w / (t4.w + 1e-8f) : x4.w - t4.w;
        __builtin_nontemporal_store(o, (f4v*)(seasonal + e));
    }
}

extern "C" void kernel_launch(void* const* d_in, const int* in_sizes, int n_in,
                              void* d_out, int out_size, void* d_ws, size_t ws_size,
                              hipStream_t stream) {
    const float* x = (const float*)d_in[0];
    float* out = (float*)d_out;
    float* trend = out;                               // output 0
    float* seasonal = out + (size_t)BB * SS * CC;     // output 1

    // stats (7*16*4096 floats = 1.75 MiB) live at the start of the seasonal
    // half; K2 consumes them before K3 overwrites seasonal. cond in d_ws.
    float* stats = seasonal;
    float* condf = (float*)d_ws;                      // 4096 floats

    k1_ring<<<dim3(BB * NSTRIP), dim3(512), 0, stream>>>(x, trend, stats);
    k2_finalize<<<dim3(NSERIES / 32), dim3(256), 0, stream>>>(stats, condf);
    k3_seasonal<<<dim3(2048), dim3(256), 0, stream>>>(x, trend, condf, seasonal);
}

// Round 13
// 41.197 us; speedup vs baseline: 1.6144x; 1.6144x over previous
//
#include <hip/hip_runtime.h>

#define SS 4096
#define CC 128
#define BB 32
#define KW 25
#define PADW 12
#define CH 64               // rows per chunk
#define SROWS (CH + KW - 1) // 88 staged rows per chunk
#define CPB 8               // chunks per block (persistent)
#define NSERIES (BB * CC)   // 4096
#define STAGE_F4 (SROWS * CC / 4) // 2816 float4s = 44 KiB per buffer

typedef float f4v __attribute__((ext_vector_type(4)));
typedef float f2v __attribute__((ext_vector_type(2)));

// ---------------- KB': single full pass --------------------------------------
// 256 blocks x 512 threads, persistent over 8 chunks, double-buffered LDS.
// Writes trend (bit-exact ascending chain) + SPECULATIVE seasonal=x/(t+eps)
// (cond=true assumed; fixup pass corrects false series) + 7 St-form stats.
__global__ __launch_bounds__(512)
void kb_pass(const float* __restrict__ x, float* __restrict__ trend,
             float* __restrict__ seasonal, float* __restrict__ stats) {
    __shared__ f4v stage[2][STAGE_F4];        // 88 KiB
    __shared__ f2v sred[7][7][64];            // 24.5 KiB stats reduce

    const int blk = blockIdx.x;               // 0..255
    const int b = blk >> 3;                   // batch
    const int q = blk & 7;                    // quarter (512 rows)
    const int tid = threadIdx.x;
    const int cp = tid & 63;                  // channel pair
    const int rg = tid >> 6;                  // row group 0..7 (8 rows/chunk)
    const float* __restrict__ xb = x + (size_t)b * SS * CC;
    f2v* __restrict__ tb = (f2v*)(trend + (size_t)b * SS * CC);
    f2v* __restrict__ sv = (f2v*)(seasonal + (size_t)b * SS * CC);

    f4v vals[6];
    auto issue = [&](int c) {                 // global -> regs (6 dwordx4)
        const int sbase = q * (CPB * CH) + c * CH - PADW;
        #pragma unroll
        for (int t = 0; t < 6; ++t) {
            const int idx = t * 512 + tid;
            if (idx < STAGE_F4) {
                const int srow = sbase + (idx >> 5);
                const int crow = srow < 0 ? 0 : (srow >= SS ? SS - 1 : srow);
                vals[t] = *(const f4v*)(xb + (size_t)crow * CC + ((idx & 31) << 2));
            }
        }
    };
    auto commit = [&](int c, int buf) {       // regs -> LDS (zero-pad edges)
        const int sbase = q * (CPB * CH) + c * CH - PADW;
        #pragma unroll
        for (int t = 0; t < 6; ++t) {
            const int idx = t * 512 + tid;
            if (idx < STAGE_F4) {
                f4v w = vals[t];
                const int srow = sbase + (idx >> 5);
                if (srow < 0 || srow >= SS) w = (f4v){0.f, 0.f, 0.f, 0.f};
                stage[buf][idx] = w;
            }
        }
    };

    issue(0);
    commit(0, 0);

    f2v Sx_e = {0,0}, Sx_o = {0,0}, Sx2 = {0,0};
    f2v St_e = {0,0}, St_o = {0,0}, St2 = {0,0}, Sxt = {0,0};

    for (int c = 0; c < CPB; ++c) {
        __syncthreads();                      // stage[c&1] ready
        const int cur = c & 1;
        if (c + 1 < CPB) issue(c + 1);        // overlap loads with compute

        const int S0 = q * (CPB * CH) + c * CH;
        const int r0 = rg * 8;
        const f2v* stg = (const f2v*)stage[cur];

        f2v win[KW];
        #pragma unroll
        for (int j = 0; j < KW; ++j) win[j] = stg[(r0 + j) * 64 + cp];

        #pragma unroll
        for (int i = 0; i < 8; ++i) {
            // fp32 sequential sum, ascending window order == XLA reduce_window
            float ax = win[0].x, ay = win[0].y;
            #pragma unroll
            for (int j = 1; j < KW; ++j) { ax += win[j].x; ay += win[j].y; }
            f2v tf;
            tf.x = ax / 25.0f;                // IEEE f32 divide, matches sums/K
            tf.y = ay / 25.0f;
            const int row = (S0 + r0 + i) * 64 + cp;
            __builtin_nontemporal_store(tf, &tb[row]);

            const f2v xv = win[PADW];         // x[s]
            f2v so;                           // speculative: cond == true
            so.x = xv.x / (tf.x + 1e-8f);
            so.y = xv.y / (tf.y + 1e-8f);
            __builtin_nontemporal_store(so, &sv[row]);

            if (i & 1) { Sx_o.x += xv.x; Sx_o.y += xv.y; St_o.x += tf.x; St_o.y += tf.y; }
            else       { Sx_e.x += xv.x; Sx_e.y += xv.y; St_e.x += tf.x; St_e.y += tf.y; }
            Sx2.x += xv.x * xv.x;  Sx2.y += xv.y * xv.y;
            St2.x += tf.x * tf.x;  St2.y += tf.y * tf.y;
            Sxt.x += xv.x * tf.x;  Sxt.y += xv.y * tf.y;

            #pragma unroll
            for (int j = 0; j < KW - 1; ++j) win[j] = win[j + 1];
            if (i < 7) win[KW - 1] = stg[(r0 + i + KW) * 64 + cp];
        }

        if (c + 1 < CPB) commit(c + 1, cur ^ 1);
    }

    // ---- combine 8 row-groups deterministically ----
    if (rg > 0) {
        f2v* me = &sred[rg - 1][0][cp];
        me[0*64] = Sx_e; me[1*64] = Sx_o; me[2*64] = Sx2;
        me[3*64] = St_e; me[4*64] = St_o; me[5*64] = St2;
        me[6*64] = Sxt;
    }
    __syncthreads();
    if (rg == 0) {
        #pragma unroll
        for (int g = 0; g < 7; ++g) {
            const f2v* gp = &sred[g][0][cp];
            Sx_e.x += gp[0*64].x; Sx_e.y += gp[0*64].y;
            Sx_o.x += gp[1*64].x; Sx_o.y += gp[1*64].y;
            Sx2.x  += gp[2*64].x; Sx2.y  += gp[2*64].y;
            St_e.x += gp[3*64].x; St_e.y += gp[3*64].y;
            St_o.x += gp[4*64].x; St_o.y += gp[4*64].y;
            St2.x  += gp[5*64].x; St2.y  += gp[5*64].y;
            Sxt.x  += gp[6*64].x; Sxt.y  += gp[6*64].y;
        }
        const int series = b * CC + 2 * cp;   // float2-aligned
        float* sp = stats + (size_t)q * NSERIES + series;
        const size_t jstride = (size_t)CPB * NSERIES;   // 8 quarter-partials
        *(f2v*)(sp + 0 * jstride) = Sx_e;
        *(f2v*)(sp + 1 * jstride) = Sx_o;
        *(f2v*)(sp + 2 * jstride) = Sx2;
        *(f2v*)(sp + 3 * jstride) = St_e;
        *(f2v*)(sp + 4 * jstride) = St_o;
        *(f2v*)(sp + 5 * jstride) = St2;
        *(f2v*)(sp + 6 * jstride) = Sxt;
    }
}

// ---------------- K2: fold 8 quarter-partials + compute cond -----------------
__global__ __launch_bounds__(256)
void k2_finalize(const float* __restrict__ stats, float* __restrict__ condf) {
    const int j = threadIdx.x >> 5;          // stat index 0..7 (7 used)
    const int sl = threadIdx.x & 31;
    const int series = blockIdx.x * 32 + sl; // 0..4095 (128 blocks)
    const size_t jstride = (size_t)CPB * NSERIES;

    __shared__ float red[32][8];
    if (j < 7) {
        const float* p = stats + j * jstride + series;
        float a = 0.f;
        #pragma unroll
        for (int k = 0; k < CPB; ++k) a += p[(size_t)k * NSERIES];
        red[sl][j] = a;
    }
    __syncthreads();
    if (threadIdx.x < 32) {
        const int me = threadIdx.x;
        const float Sx_e = red[me][0], Sx_o = red[me][1], Sx2 = red[me][2];
        const float St_e = red[me][3], St_o = red[me][4], St2 = red[me][5];
        const float Sxt = red[me][6];

        const float Sf = (float)SS;
        const float halfS = 0.5f * Sf;
        const float c_e = Sx_o / Sf;         // opposite-parity mean at even n
        const float c_o = Sx_e / Sf;
        const float sum_c = halfS * (c_e + c_o);
        const float sumsq_c = halfS * (c_e * c_e + c_o * c_o);

        const float Sw_e = 0.5f * Sx_e - St_e;
        const float Sw_o = 0.5f * Sx_o - St_o;
        const float Sw2 = 0.25f * Sx2 - Sxt + St2;

        // v1 = resid = w + c_p
        const float s1 = (Sw_e + Sw_o) + sum_c;
        const float q1 = Sw2 + 2.f * (c_e * Sw_e + c_o * Sw_o) + sumsq_c;
        const float var1 = (q1 - s1 * s1 / Sf) / (Sf - 1.f);
        // v2 = trend + resid = 0.5x + c_p
        const float s2 = 0.5f * (Sx_e + Sx_o) + sum_c;
        const float q2 = 0.25f * Sx2 + (c_e * Sx_e + c_o * Sx_o) + sumsq_c;
        const float var2 = (q2 - s2 * s2 / Sf) / (Sf - 1.f);
        // v3 = seasonal0 + resid = x - trend
        const float Sa = (Sx_e + Sx_o) - (St_e + St_o);
        const float Sa2 = Sx2 - 2.f * Sxt + St2;
        const float var3 = (Sa2 - Sa * Sa / Sf) / (Sf - 1.f);

        const float d_t = 1.f - var1 / (var2 + 1e-8f);
        const float d_s = 1.f - var1 / (var3 + 1e-8f);
        condf[blockIdx.x * 32 + me] = (d_t > 0.5f || d_s > 0.5f) ? 1.f : 0.f;
    }
}

// ---------------- K3fix: rewrite seasonal = x - t for cond-false series ------
// 512 blocks (batch, 256-row strip) x 256 threads. Fast path: read 128 conds,
// all true -> exit (~512 B/block). Slow path only touches false channels.
__global__ __launch_bounds__(256)
void k3_fixup(const float* __restrict__ x, const float* __restrict__ trend,
              const float* __restrict__ condf, float* __restrict__ seasonal) {
    const int b = blockIdx.x >> 4;
    const int strip = blockIdx.x & 15;
    const int ch = threadIdx.x & 127;
    const float cnd = condf[b * CC + ch];

    __shared__ int nfalse;
    if (threadIdx.x == 0) nfalse = 0;
    __syncthreads();
    if (threadIdx.x < 128 && cnd <= 0.5f) atomicAdd(&nfalse, 1);
    __syncthreads();
    if (nfalse == 0) return;                  // all series multiplicative

    if (cnd <= 0.5f) {
        const int half = threadIdx.x >> 7;    // 0/1
        for (int k = 0; k < 128; ++k) {
            const int s = strip * 256 + 2 * k + half;
            const size_t e = ((size_t)b * SS + s) * CC + ch;
            seasonal[e] = x[e] - trend[e];
        }
    }
}

extern "C" void kernel_launch(void* const* d_in, const int* in_sizes, int n_in,
                              void* d_out, int out_size, void* d_ws, size_t ws_size,
                              hipStream_t stream) {
    const float* x = (const float*)d_in[0];
    float* out = (float*)d_out;
    float* trend = out;                               // output 0
    float* seasonal = out + (size_t)BB * SS * CC;     // output 1

    // d_ws: [0, 16KiB) cond; [16KiB, ~912KiB) stats (7*8*4096 floats)
    float* condf = (float*)d_ws;
    float* stats = condf + NSERIES;

    kb_pass<<<dim3(BB * 8), dim3(512), 0, stream>>>(x, trend, seasonal, stats);
    k2_finalize<<<dim3(NSERIES / 32), dim3(256), 0, stream>>>(stats, condf);
    k3_fixup<<<dim3(BB * 16), dim3(256), 0, stream>>>(x, trend, condf, seasonal);
}

// Round 14
// 40.638 us; speedup vs baseline: 1.6366x; 1.0137x over previous
//
#include <hip/hip_runtime.h>

#define SS 4096
#define CC 128
#define BB 32
#define KW 25
#define PADW 12
#define CH 64               // rows per chunk
#define SROWS (CH + KW - 1) // 88 staged rows per chunk
#define CPB 8               // chunks per block (persistent)
#define NSERIES (BB * CC)   // 4096
#define STAGE_F4 (SROWS * CC / 4) // 2816 float4s = 44 KiB per buffer

typedef float f4v __attribute__((ext_vector_type(4)));
typedef float f2v __attribute__((ext_vector_type(2)));

// ---------------- KB: single full pass ---------------------------------------
// 256 blocks x 512 threads, persistent over 8 chunks, double-buffered LDS.
// Halo rows (24) are copied LDS->LDS from the previous buffer; only the 64
// new rows come from HBM. Writes trend (bit-exact ascending chain) +
// SPECULATIVE seasonal=x/(t+eps) + 7 St-form stats.
__global__ __launch_bounds__(512)
void kb_pass(const float* __restrict__ x, float* __restrict__ trend,
             float* __restrict__ seasonal, float* __restrict__ stats) {
    __shared__ f4v stage[2][STAGE_F4];        // 88 KiB
    __shared__ f2v sred[7][7][64];            // 24.5 KiB stats reduce

    const int blk = blockIdx.x;               // 0..255
    const int b = blk >> 3;                   // batch
    const int q = blk & 7;                    // quarter (512 rows)
    const int tid = threadIdx.x;
    const int cp = tid & 63;                  // channel pair
    const int rg = tid >> 6;                  // row group 0..7 (8 rows/chunk)
    const float* __restrict__ xb = x + (size_t)b * SS * CC;
    f2v* __restrict__ tb = (f2v*)(trend + (size_t)b * SS * CC);
    f2v* __restrict__ sv = (f2v*)(seasonal + (size_t)b * SS * CC);

    // ---- prologue: full 88-row stage of chunk 0 into buffer 0 ----
    {
        const int sbase = q * (CPB * CH) - PADW;
        f4v v0[6];
        #pragma unroll
        for (int t = 0; t < 6; ++t) {
            const int idx = t * 512 + tid;
            if (idx < STAGE_F4) {
                const int srow = sbase + (idx >> 5);
                const int crow = srow < 0 ? 0 : (srow >= SS ? SS - 1 : srow);
                v0[t] = *(const f4v*)(xb + (size_t)crow * CC + ((idx & 31) << 2));
            }
        }
        #pragma unroll
        for (int t = 0; t < 6; ++t) {
            const int idx = t * 512 + tid;
            if (idx < STAGE_F4) {
                f4v w = v0[t];
                const int srow = sbase + (idx >> 5);
                if (srow < 0 || srow >= SS) w = (f4v){0.f, 0.f, 0.f, 0.f};
                stage[0][idx] = w;
            }
        }
    }

    f4v vals[4];
    auto issue = [&](int c) {                 // only the 64 NEW rows (24..87)
        const int sbase = q * (CPB * CH) + c * CH - PADW;
        #pragma unroll
        for (int t = 0; t < 4; ++t) {
            const int nidx = t * 512 + tid;   // 0..2047
            const int srow = sbase + 24 + (nidx >> 5);
            const int crow = srow >= SS ? SS - 1 : srow;   // never <0 for c>=1
            vals[t] = *(const f4v*)(xb + (size_t)crow * CC + ((nidx & 31) << 2));
        }
    };
    auto commit = [&](int c, int buf) {
        // halo: staged rows 0..23 of new buffer = rows 64..87 of old buffer
        const f2v* src = (const f2v*)stage[buf ^ 1];
        f2v* dst = (f2v*)stage[buf];
        #pragma unroll
        for (int t = 0; t < 3; ++t) {
            const int hidx = t * 512 + tid;   // 0..1535 (24 rows * 64 f2v)
            dst[hidx] = src[64 * 64 + hidx];
        }
        const int sbase = q * (CPB * CH) + c * CH - PADW;
        #pragma unroll
        for (int t = 0; t < 4; ++t) {
            const int nidx = t * 512 + tid;
            const int srow = sbase + 24 + (nidx >> 5);
            f4v w = vals[t];
            if (srow >= SS) w = (f4v){0.f, 0.f, 0.f, 0.f};
            stage[buf][768 + nidx] = w;       // f4 offset: 24 rows * 32
        }
    };

    f2v Sx_e = {0,0}, Sx_o = {0,0}, Sx2 = {0,0};
    f2v St_e = {0,0}, St_o = {0,0}, St2 = {0,0}, Sxt = {0,0};

    for (int c = 0; c < CPB; ++c) {
        __syncthreads();                      // stage[c&1] ready
        const int cur = c & 1;
        if (c + 1 < CPB) issue(c + 1);        // overlap loads with compute

        const int S0 = q * (CPB * CH) + c * CH;
        const int r0 = rg * 8;
        const f2v* stg = (const f2v*)stage[cur];

        f2v win[KW];
        #pragma unroll
        for (int j = 0; j < KW; ++j) win[j] = stg[(r0 + j) * 64 + cp];

        #pragma unroll
        for (int i = 0; i < 8; ++i) {
            // fp32 sequential sum, ascending window order == XLA reduce_window
            float ax = win[0].x, ay = win[0].y;
            #pragma unroll
            for (int j = 1; j < KW; ++j) { ax += win[j].x; ay += win[j].y; }
            f2v tf;
            tf.x = ax / 25.0f;                // IEEE f32 divide, matches sums/K
            tf.y = ay / 25.0f;
            const int row = (S0 + r0 + i) * 64 + cp;
            __builtin_nontemporal_store(tf, &tb[row]);

            const f2v xv = win[PADW];         // x[s]
            f2v so;                           // speculative: cond == true
            so.x = xv.x / (tf.x + 1e-8f);
            so.y = xv.y / (tf.y + 1e-8f);
            __builtin_nontemporal_store(so, &sv[row]);

            if (i & 1) { Sx_o.x += xv.x; Sx_o.y += xv.y; St_o.x += tf.x; St_o.y += tf.y; }
            else       { Sx_e.x += xv.x; Sx_e.y += xv.y; St_e.x += tf.x; St_e.y += tf.y; }
            Sx2.x += xv.x * xv.x;  Sx2.y += xv.y * xv.y;
            St2.x += tf.x * tf.x;  St2.y += tf.y * tf.y;
            Sxt.x += xv.x * tf.x;  Sxt.y += xv.y * tf.y;

            #pragma unroll
            for (int j = 0; j < KW - 1; ++j) win[j] = win[j + 1];
            if (i < 7) win[KW - 1] = stg[(r0 + i + KW) * 64 + cp];
        }

        if (c + 1 < CPB) commit(c + 1, cur ^ 1);
    }

    // ---- combine 8 row-groups deterministically ----
    if (rg > 0) {
        f2v* me = &sred[rg - 1][0][cp];
        me[0*64] = Sx_e; me[1*64] = Sx_o; me[2*64] = Sx2;
        me[3*64] = St_e; me[4*64] = St_o; me[5*64] = St2;
        me[6*64] = Sxt;
    }
    __syncthreads();
    if (rg == 0) {
        #pragma unroll
        for (int g = 0; g < 7; ++g) {
            const f2v* gp = &sred[g][0][cp];
            Sx_e.x += gp[0*64].x; Sx_e.y += gp[0*64].y;
            Sx_o.x += gp[1*64].x; Sx_o.y += gp[1*64].y;
            Sx2.x  += gp[2*64].x; Sx2.y  += gp[2*64].y;
            St_e.x += gp[3*64].x; St_e.y += gp[3*64].y;
            St_o.x += gp[4*64].x; St_o.y += gp[4*64].y;
            St2.x  += gp[5*64].x; St2.y  += gp[5*64].y;
            Sxt.x  += gp[6*64].x; Sxt.y  += gp[6*64].y;
        }
        const int series = b * CC + 2 * cp;   // float2-aligned
        float* sp = stats + (size_t)q * NSERIES + series;
        const size_t jstride = (size_t)CPB * NSERIES;   // 8 quarter-partials
        *(f2v*)(sp + 0 * jstride) = Sx_e;
        *(f2v*)(sp + 1 * jstride) = Sx_o;
        *(f2v*)(sp + 2 * jstride) = Sx2;
        *(f2v*)(sp + 3 * jstride) = St_e;
        *(f2v*)(sp + 4 * jstride) = St_o;
        *(f2v*)(sp + 5 * jstride) = St2;
        *(f2v*)(sp + 6 * jstride) = Sxt;
    }
}

// ---------------- K2: fold partials -> cond; fix up cond-false series --------
// 128 blocks x 256 threads. For the bench input every series is cond-true,
// so the fixup loop body never runs; correctness for arbitrary inputs is
// preserved by the cooperative rewrite.
__global__ __launch_bounds__(256)
void k2_finalize_fix(const float* __restrict__ stats, const float* __restrict__ x,
                     const float* __restrict__ trend, float* __restrict__ seasonal) {
    const int j = threadIdx.x >> 5;          // stat index 0..7 (7 used)
    const int sl = threadIdx.x & 31;
    const int series0 = blockIdx.x * 32;
    const size_t jstride = (size_t)CPB * NSERIES;

    __shared__ float red[32][8];
    __shared__ int nf;
    __shared__ int flist[32];
    if (threadIdx.x == 0) nf = 0;
    if (j < 7) {
        const float* p = stats + j * jstride + series0 + sl;
        float a = 0.f;
        #pragma unroll
        for (int k = 0; k < CPB; ++k) a += p[(size_t)k * NSERIES];
        red[sl][j] = a;
    }
    __syncthreads();
    if (threadIdx.x < 32) {
        const int me = threadIdx.x;
        const float Sx_e = red[me][0], Sx_o = red[me][1], Sx2 = red[me][2];
        const float St_e = red[me][3], St_o = red[me][4], St2 = red[me][5];
        const float Sxt = red[me][6];

        const float Sf = (float)SS;
        const float halfS = 0.5f * Sf;
        const float c_e = Sx_o / Sf;         // opposite-parity mean at even n
        const float c_o = Sx_e / Sf;
        const float sum_c = halfS * (c_e + c_o);
        const float sumsq_c = halfS * (c_e * c_e + c_o * c_o);

        const float Sw_e = 0.5f * Sx_e - St_e;
        const float Sw_o = 0.5f * Sx_o - St_o;
        const float Sw2 = 0.25f * Sx2 - Sxt + St2;

        // v1 = resid = w + c_p
        const float s1 = (Sw_e + Sw_o) + sum_c;
        const float q1 = Sw2 + 2.f * (c_e * Sw_e + c_o * Sw_o) + sumsq_c;
        const float var1 = (q1 - s1 * s1 / Sf) / (Sf - 1.f);
        // v2 = trend + resid = 0.5x + c_p
        const float s2 = 0.5f * (Sx_e + Sx_o) + sum_c;
        const float q2 = 0.25f * Sx2 + (c_e * Sx_e + c_o * Sx_o) + sumsq_c;
        const float var2 = (q2 - s2 * s2 / Sf) / (Sf - 1.f);
        // v3 = seasonal0 + resid = x - trend
        const float Sa = (Sx_e + Sx_o) - (St_e + St_o);
        const float Sa2 = Sx2 - 2.f * Sxt + St2;
        const float var3 = (Sa2 - Sa * Sa / Sf) / (Sf - 1.f);

        const float d_t = 1.f - var1 / (var2 + 1e-8f);
        const float d_s = 1.f - var1 / (var3 + 1e-8f);
        if (!(d_t > 0.5f || d_s > 0.5f)) {
            const int i = atomicAdd(&nf, 1);
            flist[i] = series0 + me;
        }
    }
    __syncthreads();
    for (int fi = 0; fi < nf; ++fi) {        // additive fixup (rare path)
        const int sr = flist[fi];
        const int b = sr >> 7, ch = sr & 127;
        const float* xs = x + (size_t)b * SS * CC + ch;
        const float* ts = trend + (size_t)b * SS * CC + ch;
        float* so = seasonal + (size_t)b * SS * CC + ch;
        for (int s = threadIdx.x; s < SS; s += 256)
            so[(size_t)s * CC] = xs[(size_t)s * CC] - ts[(size_t)s * CC];
    }
}

extern "C" void kernel_launch(void* const* d_in, const int* in_sizes, int n_in,
                              void* d_out, int out_size, void* d_ws, size_t ws_size,
                              hipStream_t stream) {
    const float* x = (const float*)d_in[0];
    float* out = (float*)d_out;
    float* trend = out;                               // output 0
    float* seasonal = out + (size_t)BB * SS * CC;     // output 1

    float* stats = (float*)d_ws;                      // 7*8*4096 floats ~ 896 KiB

    kb_pass<<<dim3(BB * 8), dim3(512), 0, stream>>>(x, trend, seasonal, stats);
    k2_finalize_fix<<<dim3(NSERIES / 32), dim3(256), 0, stream>>>(stats, x, trend, seasonal);
}